// Round 1
// baseline (72.712 us; speedup 1.0000x reference)
//
#include <hip/hip_runtime.h>
#include <math.h>

#define NN 50000
#define MM 16
#define DD 128

// Kernel 0: v[0:128] = W^T a_self, v[128:256] = W^T a_nb
__global__ void compute_v_kernel(const float* __restrict__ W,
                                 const float* __restrict__ a,
                                 float* __restrict__ v) {
    int j = threadIdx.x;  // 0..127
    float vs = 0.f, vn = 0.f;
    for (int k = 0; k < DD; ++k) {
        float w = W[k * DD + j];   // coalesced across j
        vs += w * a[k];
        vn += w * a[DD + k];
    }
    v[j] = vs;
    v[DD + j] = vn;
}

// Kernel 1: per-node scores. One wave (64 lanes) per node, 2 floats/lane.
__global__ __launch_bounds__(256) void scores_kernel(
        const float* __restrict__ x, const float* __restrict__ v,
        float* __restrict__ sself, float* __restrict__ snb) {
    int wave = (blockIdx.x * blockDim.x + threadIdx.x) >> 6;
    int lane = threadIdx.x & 63;
    if (wave >= NN) return;
    const float2 xv = *reinterpret_cast<const float2*>(x + (size_t)wave * DD + 2 * lane);
    const float2 vs = *reinterpret_cast<const float2*>(v + 2 * lane);
    const float2 vn = *reinterpret_cast<const float2*>(v + DD + 2 * lane);
    float ps = xv.x * vs.x + xv.y * vs.y;
    float pn = xv.x * vn.x + xv.y * vn.y;
    for (int off = 32; off >= 1; off >>= 1) {
        ps += __shfl_down(ps, off, 64);
        pn += __shfl_down(pn, off, 64);
    }
    if (lane == 0) {
        sself[wave] = ps;
        snb[wave]  = pn;
    }
}

// Kernel 2: gather + softmax + weighted aggregate + ELU. One wave per node.
__global__ __launch_bounds__(256) void agg_kernel(
        const float* __restrict__ x, const int* __restrict__ x_nb,
        const float* __restrict__ sself, const float* __restrict__ snb,
        float* __restrict__ out) {
    int node = (blockIdx.x * blockDim.x + threadIdx.x) >> 6;
    int lane = threadIdx.x & 63;
    if (node >= NN) return;

    // Every lane handles neighbor m = lane & 15 (4x redundant, cache-resident).
    int m = lane & 15;
    int idxv = x_nb[(size_t)node * MM + m] - 1;
    float s0 = sself[node];
    float sv = s0 + snb[idxv];
    float ev = sv > 0.f ? sv : 0.01f * sv;   // leaky_relu(0.01)

    // softmax over the 16-group (xor shuffles with masks 8,4,2,1)
    float mx = ev;
    for (int off = 8; off >= 1; off >>= 1) mx = fmaxf(mx, __shfl_xor(mx, off, 64));
    float ex = __expf(ev - mx);
    float sum = ex;
    for (int off = 8; off >= 1; off >>= 1) sum += __shfl_xor(sum, off, 64);
    float alpha = ex / sum;

    // Weighted sum of 16 gathered rows; lane owns d = 2*lane, 2*lane+1.
    float ux = 0.f, uy = 0.f;
#pragma unroll
    for (int mm = 0; mm < MM; ++mm) {
        int id   = __shfl(idxv, mm, 64);   // lane mm holds neighbor mm
        float al = __shfl(alpha, mm, 64);
        const float2 xv = *reinterpret_cast<const float2*>(x + (size_t)id * DD + 2 * lane);
        ux += al * xv.x;
        uy += al * xv.y;
    }
    // ELU
    ux = ux > 0.f ? ux : __expf(ux) - 1.f;
    uy = uy > 0.f ? uy : __expf(uy) - 1.f;
    float2 o; o.x = ux; o.y = uy;
    *reinterpret_cast<float2*>(out + (size_t)node * DD + 2 * lane) = o;
}

extern "C" void kernel_launch(void* const* d_in, const int* in_sizes, int n_in,
                              void* d_out, int out_size, void* d_ws, size_t ws_size,
                              hipStream_t stream) {
    const float* x    = (const float*)d_in[0];
    const int*   x_nb = (const int*)d_in[1];
    const float* W    = (const float*)d_in[2];
    const float* a    = (const float*)d_in[3];
    float* out = (float*)d_out;

    // workspace layout: v (256 floats) | sself (NN) | snb (NN)
    float* v     = (float*)d_ws;
    float* sself = v + 256;
    float* snb   = sself + NN;

    compute_v_kernel<<<1, DD, 0, stream>>>(W, a, v);

    int waves = NN;                     // one wave per node
    int blocks = (waves * 64 + 255) / 256;
    scores_kernel<<<blocks, 256, 0, stream>>>(x, v, sself, snb);
    agg_kernel<<<blocks, 256, 0, stream>>>(x, x_nb, sself, snb, out);
}

// Round 2
// 49.745 us; speedup vs baseline: 1.4617x; 1.4617x over previous
//
#include <hip/hip_runtime.h>
#include <math.h>

#define NN 50000
#define MM 16
#define DD 128

// ---- bf16 round-to-nearest-even helpers (data has no NaN/Inf) ----
__device__ __forceinline__ unsigned bf16rn(float f) {
    unsigned u = __float_as_uint(f);
    return (u + 0x7fffu + ((u >> 16) & 1u)) >> 16;
}
__device__ __forceinline__ float bf16lo(unsigned p) {   // low 16 bits -> float
    return __uint_as_float(p << 16);
}
__device__ __forceinline__ float bf16hi(unsigned p) {   // high 16 bits -> float
    return __uint_as_float(p & 0xffff0000u);
}

// Kernel 0: v[0:128] = W^T a_self, v[128:256] = W^T a_nb
__global__ void compute_v_kernel(const float* __restrict__ W,
                                 const float* __restrict__ a,
                                 float* __restrict__ v) {
    int j = threadIdx.x;  // 0..127
    float vs = 0.f, vn = 0.f;
    for (int k = 0; k < DD; ++k) {
        float w = W[k * DD + j];   // coalesced across j
        vs += w * a[k];
        vn += w * a[DD + k];
    }
    v[j] = vs;
    v[DD + j] = vn;
}

// Kernel 1 (fused): per-node scores (fp32) + emit packed-bf16 copy of x.
// One wave per node; lane owns elements {2*lane, 2*lane+1}.
__global__ __launch_bounds__(256) void prep_kernel(
        const float* __restrict__ x, const float* __restrict__ v,
        float* __restrict__ sself, float* __restrict__ snb,
        unsigned* __restrict__ xh) {
    int node = (blockIdx.x * blockDim.x + threadIdx.x) >> 6;
    int lane = threadIdx.x & 63;
    if (node >= NN) return;
    const float2 xv = *reinterpret_cast<const float2*>(x + (size_t)node * DD + 2 * lane);
    const float2 vs = *reinterpret_cast<const float2*>(v + 2 * lane);
    const float2 vn = *reinterpret_cast<const float2*>(v + DD + 2 * lane);

    // packed bf16 copy (elem0 in low half, elem1 in high half)
    xh[(size_t)node * (DD / 2) + lane] = bf16rn(xv.x) | (bf16rn(xv.y) << 16);

    float ps = xv.x * vs.x + xv.y * vs.y;
    float pn = xv.x * vn.x + xv.y * vn.y;
    for (int off = 32; off >= 1; off >>= 1) {
        ps += __shfl_down(ps, off, 64);
        pn += __shfl_down(pn, off, 64);
    }
    if (lane == 0) {
        sself[node] = ps;
        snb[node]  = pn;
    }
}

// Kernel 2: gather (bf16 rows) + softmax + weighted aggregate + ELU.
__global__ __launch_bounds__(256) void agg_bf16_kernel(
        const unsigned* __restrict__ xh, const int* __restrict__ x_nb,
        const float* __restrict__ sself, const float* __restrict__ snb,
        float* __restrict__ out) {
    int node = (blockIdx.x * blockDim.x + threadIdx.x) >> 6;
    int lane = threadIdx.x & 63;
    if (node >= NN) return;

    int m = lane & 15;
    int idxv = x_nb[(size_t)node * MM + m] - 1;
    float s0 = sself[node];
    float sv = s0 + snb[idxv];
    float ev = sv > 0.f ? sv : 0.01f * sv;   // leaky_relu(0.01)

    float mx = ev;
    for (int off = 8; off >= 1; off >>= 1) mx = fmaxf(mx, __shfl_xor(mx, off, 64));
    float ex = __expf(ev - mx);
    float sum = ex;
    for (int off = 8; off >= 1; off >>= 1) sum += __shfl_xor(sum, off, 64);
    float alpha = ex / sum;

    float ux = 0.f, uy = 0.f;
#pragma unroll
    for (int mm = 0; mm < MM; ++mm) {
        int id   = __shfl(idxv, mm, 64);
        float al = __shfl(alpha, mm, 64);
        unsigned p = xh[(size_t)id * (DD / 2) + lane];  // 4B/lane, 256B/row
        ux += al * bf16lo(p);
        uy += al * bf16hi(p);
    }
    ux = ux > 0.f ? ux : __expf(ux) - 1.f;
    uy = uy > 0.f ? uy : __expf(uy) - 1.f;
    float2 o; o.x = ux; o.y = uy;
    *reinterpret_cast<float2*>(out + (size_t)node * DD + 2 * lane) = o;
}

// ---------- fallback fp32 path (if ws too small for xh) ----------
__global__ __launch_bounds__(256) void scores_kernel(
        const float* __restrict__ x, const float* __restrict__ v,
        float* __restrict__ sself, float* __restrict__ snb) {
    int wave = (blockIdx.x * blockDim.x + threadIdx.x) >> 6;
    int lane = threadIdx.x & 63;
    if (wave >= NN) return;
    const float2 xv = *reinterpret_cast<const float2*>(x + (size_t)wave * DD + 2 * lane);
    const float2 vs = *reinterpret_cast<const float2*>(v + 2 * lane);
    const float2 vn = *reinterpret_cast<const float2*>(v + DD + 2 * lane);
    float ps = xv.x * vs.x + xv.y * vs.y;
    float pn = xv.x * vn.x + xv.y * vn.y;
    for (int off = 32; off >= 1; off >>= 1) {
        ps += __shfl_down(ps, off, 64);
        pn += __shfl_down(pn, off, 64);
    }
    if (lane == 0) { sself[wave] = ps; snb[wave] = pn; }
}

__global__ __launch_bounds__(256) void agg_kernel(
        const float* __restrict__ x, const int* __restrict__ x_nb,
        const float* __restrict__ sself, const float* __restrict__ snb,
        float* __restrict__ out) {
    int node = (blockIdx.x * blockDim.x + threadIdx.x) >> 6;
    int lane = threadIdx.x & 63;
    if (node >= NN) return;
    int m = lane & 15;
    int idxv = x_nb[(size_t)node * MM + m] - 1;
    float sv = sself[node] + snb[idxv];
    float ev = sv > 0.f ? sv : 0.01f * sv;
    float mx = ev;
    for (int off = 8; off >= 1; off >>= 1) mx = fmaxf(mx, __shfl_xor(mx, off, 64));
    float ex = __expf(ev - mx);
    float sum = ex;
    for (int off = 8; off >= 1; off >>= 1) sum += __shfl_xor(sum, off, 64);
    float alpha = ex / sum;
    float ux = 0.f, uy = 0.f;
#pragma unroll
    for (int mm = 0; mm < MM; ++mm) {
        int id   = __shfl(idxv, mm, 64);
        float al = __shfl(alpha, mm, 64);
        const float2 xv = *reinterpret_cast<const float2*>(x + (size_t)id * DD + 2 * lane);
        ux += al * xv.x;
        uy += al * xv.y;
    }
    ux = ux > 0.f ? ux : __expf(ux) - 1.f;
    uy = uy > 0.f ? uy : __expf(uy) - 1.f;
    float2 o; o.x = ux; o.y = uy;
    *reinterpret_cast<float2*>(out + (size_t)node * DD + 2 * lane) = o;
}

extern "C" void kernel_launch(void* const* d_in, const int* in_sizes, int n_in,
                              void* d_out, int out_size, void* d_ws, size_t ws_size,
                              hipStream_t stream) {
    const float* x    = (const float*)d_in[0];
    const int*   x_nb = (const int*)d_in[1];
    const float* W    = (const float*)d_in[2];
    const float* a    = (const float*)d_in[3];
    float* out = (float*)d_out;

    // ws layout: v (256 f32) | sself (NN) | snb (NN) | xh (NN*64 u32)
    float* v     = (float*)d_ws;
    float* sself = v + 256;
    float* snb   = sself + NN;
    unsigned* xh = (unsigned*)(snb + NN);

    const size_t need_bf16 = (size_t)(256 + 2 * NN) * 4 + (size_t)NN * (DD / 2) * 4;

    compute_v_kernel<<<1, DD, 0, stream>>>(W, a, v);

    int blocks = (NN * 64 + 255) / 256;
    if (ws_size >= need_bf16) {
        prep_kernel<<<blocks, 256, 0, stream>>>(x, v, sself, snb, xh);
        agg_bf16_kernel<<<blocks, 256, 0, stream>>>(xh, x_nb, sself, snb, out);
    } else {
        scores_kernel<<<blocks, 256, 0, stream>>>(x, v, sself, snb);
        agg_kernel<<<blocks, 256, 0, stream>>>(x, x_nb, sself, snb, out);
    }
}

// Round 3
// 46.144 us; speedup vs baseline: 1.5758x; 1.0780x over previous
//
#include <hip/hip_runtime.h>
#include <math.h>

#define NN 50000
#define MM 16
#define DD 128

// Kernel 0: v[0:128] = W^T a_self, v[128:256] = W^T a_nb
// 512 threads: j = tid&127 (output col), kc = tid>>7 (k-chunk of 32), LDS reduce.
__global__ __launch_bounds__(512) void compute_v_kernel(
        const float* __restrict__ W, const float* __restrict__ a,
        float* __restrict__ v) {
    __shared__ float svs[4][DD];
    __shared__ float svn[4][DD];
    int j  = threadIdx.x & 127;
    int kc = threadIdx.x >> 7;         // 0..3
    float vs = 0.f, vn = 0.f;
#pragma unroll 4
    for (int k = kc * 32; k < kc * 32 + 32; ++k) {
        float w = W[k * DD + j];       // coalesced across j; a[k] wave-uniform
        vs += w * a[k];
        vn += w * a[DD + k];
    }
    svs[kc][j] = vs;
    svn[kc][j] = vn;
    __syncthreads();
    if (kc == 0) {
        v[j]      = svs[0][j] + svs[1][j] + svs[2][j] + svs[3][j];
        v[DD + j] = svn[0][j] + svn[1][j] + svn[2][j] + svn[3][j];
    }
}

// Kernel 1 (fused): per-node scores (fp32) + row-scaled int8 copy of x.
// One wave per node; lane owns elements {2*lane, 2*lane+1}.
__global__ __launch_bounds__(256) void prep_kernel(
        const float* __restrict__ x, const float* __restrict__ v,
        float* __restrict__ sself, float* __restrict__ snb,
        float* __restrict__ scale, unsigned short* __restrict__ xq) {
    int node = (blockIdx.x * blockDim.x + threadIdx.x) >> 6;
    int lane = threadIdx.x & 63;
    if (node >= NN) return;
    const float2 xv = *reinterpret_cast<const float2*>(x + (size_t)node * DD + 2 * lane);
    const float2 vs = *reinterpret_cast<const float2*>(v + 2 * lane);
    const float2 vn = *reinterpret_cast<const float2*>(v + DD + 2 * lane);

    // row max(|x|) across the wave
    float am = fmaxf(fabsf(xv.x), fabsf(xv.y));
    for (int off = 32; off >= 1; off >>= 1) am = fmaxf(am, __shfl_xor(am, off, 64));
    float sc  = am / 127.f;
    float inv = am > 0.f ? 127.f / am : 0.f;

    int q0 = (int)rintf(xv.x * inv);
    int q1 = (int)rintf(xv.y * inv);
    xq[(size_t)node * (DD / 2) + lane] =
        (unsigned short)((q0 & 0xff) | ((q1 & 0xff) << 8));

    // fp32 scores
    float ps = xv.x * vs.x + xv.y * vs.y;
    float pn = xv.x * vn.x + xv.y * vn.y;
    for (int off = 32; off >= 1; off >>= 1) {
        ps += __shfl_down(ps, off, 64);
        pn += __shfl_down(pn, off, 64);
    }
    if (lane == 0) {
        sself[node] = ps;
        snb[node]   = pn;
        scale[node] = sc;
    }
}

// Kernel 2: gather (int8 rows) + softmax + weighted aggregate + ELU.
__global__ __launch_bounds__(256) void agg_q8_kernel(
        const unsigned short* __restrict__ xq, const int* __restrict__ x_nb,
        const float* __restrict__ sself, const float* __restrict__ snb,
        const float* __restrict__ scale, float* __restrict__ out) {
    int node = (blockIdx.x * blockDim.x + threadIdx.x) >> 6;
    int lane = threadIdx.x & 63;
    if (node >= NN) return;

    int m = lane & 15;
    int idxv = x_nb[(size_t)node * MM + m] - 1;
    float sv = sself[node] + snb[idxv];
    float ev = sv > 0.f ? sv : 0.01f * sv;   // leaky_relu(0.01)

    float mx = ev;
    for (int off = 8; off >= 1; off >>= 1) mx = fmaxf(mx, __shfl_xor(mx, off, 64));
    float ex = __expf(ev - mx);
    float sum = ex;
    for (int off = 8; off >= 1; off >>= 1) sum += __shfl_xor(sum, off, 64);
    float coef = (ex / sum) * scale[idxv];   // alpha * per-row dequant scale

    float ux = 0.f, uy = 0.f;
#pragma unroll
    for (int mm = 0; mm < MM; ++mm) {
        int id   = __shfl(idxv, mm, 64);
        float cf = __shfl(coef, mm, 64);
        unsigned p = xq[(size_t)id * (DD / 2) + lane];  // 2B/lane, 128B/row
        float lo = (float)(signed char)(p & 0xff);
        float hi = (float)(signed char)((p >> 8) & 0xff);
        ux += cf * lo;
        uy += cf * hi;
    }
    ux = ux > 0.f ? ux : __expf(ux) - 1.f;
    uy = uy > 0.f ? uy : __expf(uy) - 1.f;
    float2 o; o.x = ux; o.y = uy;
    *reinterpret_cast<float2*>(out + (size_t)node * DD + 2 * lane) = o;
}

// ---------- fallback fp32 path (if ws too small) ----------
__global__ __launch_bounds__(256) void scores_kernel(
        const float* __restrict__ x, const float* __restrict__ v,
        float* __restrict__ sself, float* __restrict__ snb) {
    int wave = (blockIdx.x * blockDim.x + threadIdx.x) >> 6;
    int lane = threadIdx.x & 63;
    if (wave >= NN) return;
    const float2 xv = *reinterpret_cast<const float2*>(x + (size_t)wave * DD + 2 * lane);
    const float2 vs = *reinterpret_cast<const float2*>(v + 2 * lane);
    const float2 vn = *reinterpret_cast<const float2*>(v + DD + 2 * lane);
    float ps = xv.x * vs.x + xv.y * vs.y;
    float pn = xv.x * vn.x + xv.y * vn.y;
    for (int off = 32; off >= 1; off >>= 1) {
        ps += __shfl_down(ps, off, 64);
        pn += __shfl_down(pn, off, 64);
    }
    if (lane == 0) { sself[wave] = ps; snb[wave] = pn; }
}

__global__ __launch_bounds__(256) void agg_kernel(
        const float* __restrict__ x, const int* __restrict__ x_nb,
        const float* __restrict__ sself, const float* __restrict__ snb,
        float* __restrict__ out) {
    int node = (blockIdx.x * blockDim.x + threadIdx.x) >> 6;
    int lane = threadIdx.x & 63;
    if (node >= NN) return;
    int m = lane & 15;
    int idxv = x_nb[(size_t)node * MM + m] - 1;
    float sv = sself[node] + snb[idxv];
    float ev = sv > 0.f ? sv : 0.01f * sv;
    float mx = ev;
    for (int off = 8; off >= 1; off >>= 1) mx = fmaxf(mx, __shfl_xor(mx, off, 64));
    float ex = __expf(ev - mx);
    float sum = ex;
    for (int off = 8; off >= 1; off >>= 1) sum += __shfl_xor(sum, off, 64);
    float alpha = ex / sum;
    float ux = 0.f, uy = 0.f;
#pragma unroll
    for (int mm = 0; mm < MM; ++mm) {
        int id   = __shfl(idxv, mm, 64);
        float al = __shfl(alpha, mm, 64);
        const float2 xv = *reinterpret_cast<const float2*>(x + (size_t)id * DD + 2 * lane);
        ux += al * xv.x;
        uy += al * xv.y;
    }
    ux = ux > 0.f ? ux : __expf(ux) - 1.f;
    uy = uy > 0.f ? uy : __expf(uy) - 1.f;
    float2 o; o.x = ux; o.y = uy;
    *reinterpret_cast<float2*>(out + (size_t)node * DD + 2 * lane) = o;
}

extern "C" void kernel_launch(void* const* d_in, const int* in_sizes, int n_in,
                              void* d_out, int out_size, void* d_ws, size_t ws_size,
                              hipStream_t stream) {
    const float* x    = (const float*)d_in[0];
    const int*   x_nb = (const int*)d_in[1];
    const float* W    = (const float*)d_in[2];
    const float* a    = (const float*)d_in[3];
    float* out = (float*)d_out;

    // ws layout: v (256 f32) | sself (NN) | snb (NN) | scale (NN) | xq (NN*64 u16)
    float* v     = (float*)d_ws;
    float* sself = v + 256;
    float* snb   = sself + NN;
    float* scale = snb + NN;
    unsigned short* xq = (unsigned short*)(scale + NN);

    const size_t need_q8 = (size_t)(256 + 3 * NN) * 4 + (size_t)NN * (DD / 2) * 2;

    compute_v_kernel<<<1, 512, 0, stream>>>(W, a, v);

    int blocks = (NN * 64 + 255) / 256;
    if (ws_size >= need_q8) {
        prep_kernel<<<blocks, 256, 0, stream>>>(x, v, sself, snb, scale, xq);
        agg_q8_kernel<<<blocks, 256, 0, stream>>>(xq, x_nb, sself, snb, scale, out);
    } else {
        scores_kernel<<<blocks, 256, 0, stream>>>(x, v, sself, snb);
        agg_kernel<<<blocks, 256, 0, stream>>>(x, x_nb, sself, snb, out);
    }
}